// Round 3
// baseline (1238.502 us; speedup 1.0000x reference)
//
#include <hip/hip_runtime.h>
#include <math.h>

#define B_ROWS 4096
#define NSTR 4
#define C_DIM 4096
#define NC 16384      // NSTR*C_DIM
#define NC4 4096      // NC/4 (float4 per batch row)
#define C4 1024       // C_DIM/4 (float4 per stream)

// ---------------------------------------------------------------------------
// Kernel 0: repack phi into one contiguous [24][16384] buffer.
// Row order: [pre0..3, post0..3, res0..3 | res4..15]
//   rows 0..11  -> lane-half A outputs, rows 12..23 -> lane-half B outputs
// ---------------------------------------------------------------------------
__global__ void repack_kernel(
    const float4* __restrict__ pre4,
    const float4* __restrict__ post4,
    const float4* __restrict__ res4,
    float4* __restrict__ phiws4)
{
    const int idx = blockIdx.x * blockDim.x + threadIdx.x;   // 0 .. 24*4096-1
    if (idx >= 24 * NC4) return;
    const int row = idx / NC4;
    const int k4  = idx % NC4;
    float4 v;
    if (row < 4)        v = pre4[row * NC4 + k4];
    else if (row < 8)   v = post4[(row - 4) * NC4 + k4];
    else                v = res4[(row - 8) * NC4 + k4];   // rows 8..23 -> res0..15
    phiws4[idx] = v;
}

// ---------------------------------------------------------------------------
// Kernel 1: projections. Grid = (B_ROWS/4) x 2 K-halves -> 2048 blocks
// (8 blocks/CU = 32 waves/CU = 100% occupancy at 64 VGPR).
// Block = 4 batch rows x one K-half; 4 waves = K-eighths.
// Within a wave: lanes 0-31 (half A) accumulate outputs {pre0-3, post0-3,
// res0-3, ssq}; lanes 32-63 (half B) accumulate {res4-15}. Both halves read
// identical x addresses (HW broadcast); phi rows differ per half via the
// repacked phiws layout. Partial dots written per K-half; finalize sums.
// ---------------------------------------------------------------------------
__global__ __launch_bounds__(256, 8) void proj_kernel(
    const float* __restrict__ x,
    const float* __restrict__ phiws,
    float* __restrict__ dots_part)   // [2][B_ROWS][25]
{
    const float4* __restrict__ x4    = reinterpret_cast<const float4*>(x);
    const float4* __restrict__ phi4  = reinterpret_cast<const float4*>(phiws);

    const int bid  = blockIdx.x;
    const int kb   = bid & 1;            // K-half
    const int b0   = (bid >> 1) * 4;     // first batch row
    const int wave = threadIdx.x >> 6;
    const int lane = threadIdx.x & 63;
    const int half = lane >> 5;          // 0 = group A, 1 = group B
    const int l31  = lane & 31;
    const int phirow0 = half * 12;       // first phiws row for this half

    float acc[4][13];
#pragma unroll
    for (int r = 0; r < 4; ++r)
#pragma unroll
        for (int j = 0; j < 13; ++j) acc[r][j] = 0.f;

    // this block covers float4 indices [kb*2048, kb*2048+2048); wave gets 512
    const int kbase = kb * 2048 + wave * 512;

    for (int s = 0; s < 16; ++s) {
        const int k4 = kbase + s * 32 + l31;

        float4 xv[4];
#pragma unroll
        for (int r = 0; r < 4; ++r)
            xv[r] = x4[(size_t)(b0 + r) * NC4 + k4];

        // ssq (both halves compute it over identical addresses; only A's is used)
#pragma unroll
        for (int r = 0; r < 4; ++r)
            acc[r][12] += xv[r].x*xv[r].x + xv[r].y*xv[r].y
                        + xv[r].z*xv[r].z + xv[r].w*xv[r].w;

        // 12 phi rows for this half, staged in groups of 4 to limit live regs
#pragma unroll
        for (int g = 0; g < 3; ++g) {
            float4 p[4];
#pragma unroll
            for (int jj = 0; jj < 4; ++jj)
                p[jj] = phi4[(size_t)(phirow0 + g * 4 + jj) * NC4 + k4];
#pragma unroll
            for (int jj = 0; jj < 4; ++jj)
#pragma unroll
                for (int r = 0; r < 4; ++r)
                    acc[r][g * 4 + jj] += xv[r].x*p[jj].x + xv[r].y*p[jj].y
                                        + xv[r].z*p[jj].z + xv[r].w*p[jj].w;
        }
    }

    // butterfly reduce within each 32-lane half (offsets < 32 stay in-half)
#pragma unroll
    for (int r = 0; r < 4; ++r)
#pragma unroll
        for (int j = 0; j < 13; ++j) {
            float v = acc[r][j];
#pragma unroll
            for (int off = 16; off > 0; off >>= 1)
                v += __shfl_xor(v, off, 64);
            acc[r][j] = v;
        }

    __shared__ float red[4][2][4][13];   // [wave][half][row][j]
    if (l31 < 13) {
#pragma unroll
        for (int r = 0; r < 4; ++r)
            red[wave][half][r][l31] = acc[r][l31];
    }
    __syncthreads();

    // final cross-wave sum; 100 threads -> dots_part[kb][4 rows][25]
    const int t = threadIdx.x;
    if (t < 100) {
        const int r = t / 25, o = t % 25;
        int h, j;
        if (o < 12)      { h = 0; j = o; }        // pre0-3, post0-3, res0-3
        else if (o < 24) { h = 1; j = o - 12; }   // res4-15
        else             { h = 0; j = 12; }       // ssq
        const float s = red[0][h][r][j] + red[1][h][r][j]
                      + red[2][h][r][j] + red[3][h][r][j];
        dots_part[((size_t)kb * B_ROWS + (b0 + r)) * 25 + o] = s;
    }
}

// ---------------------------------------------------------------------------
// Kernel 2: per-row finalize: sum K-halves, rms factor, softmax, 2*sigmoid,
// Sinkhorn(20).
// dots layout: [0..3]=pre, [4..7]=post, [8..23]=res, [24]=ssq
// params layout: [0..3]=H_pre, [4..7]=H_post, [8..23]=M (row-major 4x4)
// ---------------------------------------------------------------------------
__global__ void finalize_kernel(
    const float* __restrict__ dots_part,
    const float* __restrict__ b_pre,
    const float* __restrict__ b_post,
    const float* __restrict__ b_res,
    const float* __restrict__ alpha_pre,
    const float* __restrict__ alpha_post,
    const float* __restrict__ alpha_res,
    float* __restrict__ params)
{
    const int row = blockIdx.x * blockDim.x + threadIdx.x;
    if (row >= B_ROWS) return;

    const float* d0 = dots_part + (size_t)row * 25;
    const float* d1 = dots_part + ((size_t)B_ROWS + row) * 25;
    float d[25];
#pragma unroll
    for (int o = 0; o < 25; ++o) d[o] = d0[o] + d1[o];

    const float inv_rms = rsqrtf(d[24] * (1.f / (float)NC) + 1e-8f);
    const float ap  = alpha_pre[0];
    const float apo = alpha_post[0];
    const float ar  = alpha_res[0];

    // softmax(h_pre)
    float hp[4];
    float mx = -1e30f;
#pragma unroll
    for (int j = 0; j < 4; ++j) {
        hp[j] = ap * d[j] * inv_rms + b_pre[j];
        mx = fmaxf(mx, hp[j]);
    }
    float e[4], s = 0.f;
#pragma unroll
    for (int j = 0; j < 4; ++j) { e[j] = expf(hp[j] - mx); s += e[j]; }
    float Hpre[4];
#pragma unroll
    for (int j = 0; j < 4; ++j) Hpre[j] = e[j] / s;

    // 2*sigmoid(h_post)
    float Hpost[4];
#pragma unroll
    for (int j = 0; j < 4; ++j) {
        const float h = apo * d[4 + j] * inv_rms + b_post[j];
        Hpost[j] = 2.f / (1.f + expf(-h));
    }

    // Sinkhorn on exp(h_res)
    float M[16];
#pragma unroll
    for (int k = 0; k < 16; ++k)
        M[k] = expf(ar * d[8 + k] * inv_rms + b_res[k]);

    for (int it = 0; it < 20; ++it) {
#pragma unroll
        for (int i = 0; i < 4; ++i) {
            const float rs = M[i*4+0] + M[i*4+1] + M[i*4+2] + M[i*4+3] + 1e-8f;
#pragma unroll
            for (int j = 0; j < 4; ++j) M[i*4+j] = M[i*4+j] / rs;
        }
#pragma unroll
        for (int j = 0; j < 4; ++j) {
            const float cs = M[0*4+j] + M[1*4+j] + M[2*4+j] + M[3*4+j] + 1e-8f;
#pragma unroll
            for (int i = 0; i < 4; ++i) M[i*4+j] = M[i*4+j] / cs;
        }
    }

    float* p = params + (size_t)row * 24;
#pragma unroll
    for (int j = 0; j < 4; ++j)  p[j]     = Hpre[j];
#pragma unroll
    for (int j = 0; j < 4; ++j)  p[4 + j] = Hpost[j];
#pragma unroll
    for (int k = 0; k < 16; ++k) p[8 + k] = M[k];
}

// ---------------------------------------------------------------------------
// Kernel 3: output. One block per batch row; x row held in registers
// (64 floats/thread), block-reduced RMS of x_agg, then fused epilogue.
// ---------------------------------------------------------------------------
__global__ __launch_bounds__(256, 2) void out_kernel(
    const float* __restrict__ x,
    const float* __restrict__ w,
    const float* __restrict__ params,
    float* __restrict__ out)
{
    const float4* __restrict__ x4 = reinterpret_cast<const float4*>(x);
    const float4* __restrict__ w4 = reinterpret_cast<const float4*>(w);
    float4* __restrict__ out4 = reinterpret_cast<float4*>(out);

    const int b = blockIdx.x;
    const float* __restrict__ p = params + (size_t)b * 24;

    float Hpre[4], Hpost[4], M[16];
#pragma unroll
    for (int j = 0; j < 4; ++j)  Hpre[j]  = p[j];
#pragma unroll
    for (int j = 0; j < 4; ++j)  Hpost[j] = p[4 + j];
#pragma unroll
    for (int k = 0; k < 16; ++k) M[k]     = p[8 + k];

    const int t = threadIdx.x;
    const size_t base = (size_t)b * NC4;

    float4 xv[4][4];  // [u][stream]
    float4 agg[4];
    float ssq = 0.f;

#pragma unroll
    for (int u = 0; u < 4; ++u) {
        const int c4 = u * 256 + t;
#pragma unroll
        for (int n = 0; n < 4; ++n)
            xv[u][n] = x4[base + (size_t)n * C4 + c4];

        float4 a;
        a.x = Hpre[0]*xv[u][0].x + Hpre[1]*xv[u][1].x + Hpre[2]*xv[u][2].x + Hpre[3]*xv[u][3].x;
        a.y = Hpre[0]*xv[u][0].y + Hpre[1]*xv[u][1].y + Hpre[2]*xv[u][2].y + Hpre[3]*xv[u][3].y;
        a.z = Hpre[0]*xv[u][0].z + Hpre[1]*xv[u][1].z + Hpre[2]*xv[u][2].z + Hpre[3]*xv[u][3].z;
        a.w = Hpre[0]*xv[u][0].w + Hpre[1]*xv[u][1].w + Hpre[2]*xv[u][2].w + Hpre[3]*xv[u][3].w;
        agg[u] = a;
        ssq += a.x*a.x + a.y*a.y + a.z*a.z + a.w*a.w;
    }

    // block-wide sum of ssq
#pragma unroll
    for (int off = 32; off > 0; off >>= 1)
        ssq += __shfl_xor(ssq, off, 64);
    __shared__ float red[4];
    if ((t & 63) == 0) red[t >> 6] = ssq;
    __syncthreads();
    const float total = red[0] + red[1] + red[2] + red[3];
    const float inv = rsqrtf(total * (1.f / (float)C_DIM) + 1e-5f);

#pragma unroll
    for (int u = 0; u < 4; ++u) {
        const int c4 = u * 256 + t;
        const float4 wv = w4[c4];
        float4 y;
        y.x = agg[u].x * inv * wv.x;
        y.y = agg[u].y * inv * wv.y;
        y.z = agg[u].z * inv * wv.z;
        y.w = agg[u].w * inv * wv.w;

#pragma unroll
        for (int i = 0; i < 4; ++i) {
            float4 o;
            o.x = Hpost[i]*y.x + M[i*4+0]*xv[u][0].x + M[i*4+1]*xv[u][1].x
                               + M[i*4+2]*xv[u][2].x + M[i*4+3]*xv[u][3].x;
            o.y = Hpost[i]*y.y + M[i*4+0]*xv[u][0].y + M[i*4+1]*xv[u][1].y
                               + M[i*4+2]*xv[u][2].y + M[i*4+3]*xv[u][3].y;
            o.z = Hpost[i]*y.z + M[i*4+0]*xv[u][0].z + M[i*4+1]*xv[u][1].z
                               + M[i*4+2]*xv[u][2].z + M[i*4+3]*xv[u][3].z;
            o.w = Hpost[i]*y.w + M[i*4+0]*xv[u][0].w + M[i*4+1]*xv[u][1].w
                               + M[i*4+2]*xv[u][2].w + M[i*4+3]*xv[u][3].w;
            out4[base + (size_t)i * C4 + c4] = o;
        }
    }
}

// ---------------------------------------------------------------------------
extern "C" void kernel_launch(void* const* d_in, const int* in_sizes, int n_in,
                              void* d_out, int out_size, void* d_ws, size_t ws_size,
                              hipStream_t stream) {
    const float* x        = (const float*)d_in[0];
    const float* w        = (const float*)d_in[1];
    const float* phi_pre  = (const float*)d_in[2];
    const float* phi_post = (const float*)d_in[3];
    const float* phi_res  = (const float*)d_in[4];
    const float* b_pre    = (const float*)d_in[5];
    const float* b_post   = (const float*)d_in[6];
    const float* b_res    = (const float*)d_in[7];
    const float* a_pre    = (const float*)d_in[8];
    const float* a_post   = (const float*)d_in[9];
    const float* a_res    = (const float*)d_in[10];
    float* out = (float*)d_out;

    float* dots_part = (float*)d_ws;                        // [2][4096][25]
    float* params    = dots_part + (size_t)2 * B_ROWS * 25; // [4096][24]
    float* phiws     = params + (size_t)B_ROWS * 24;        // [24][16384]

    hipLaunchKernelGGL(repack_kernel, dim3((24 * NC4 + 255) / 256), dim3(256), 0, stream,
                       (const float4*)phi_pre, (const float4*)phi_post,
                       (const float4*)phi_res, (float4*)phiws);
    hipLaunchKernelGGL(proj_kernel, dim3(B_ROWS / 2), dim3(256), 0, stream,
                       x, phiws, dots_part);
    hipLaunchKernelGGL(finalize_kernel, dim3(B_ROWS / 256), dim3(256), 0, stream,
                       dots_part, b_pre, b_post, b_res, a_pre, a_post, a_res, params);
    hipLaunchKernelGGL(out_kernel, dim3(B_ROWS), dim3(256), 0, stream,
                       x, w, params, out);
}

// Round 4
// 317.240 us; speedup vs baseline: 3.9040x; 3.9040x over previous
//
#include <hip/hip_runtime.h>
#include <math.h>

#define B_ROWS 4096
#define NSTR 4
#define C_DIM 4096
#define NC 16384      // NSTR*C_DIM
#define NC4 4096      // NC/4 (float4 per batch row)
#define C4 1024       // C_DIM/4 (float4 per stream)

// ---------------------------------------------------------------------------
// Kernel 0: repack phi into one contiguous [24][16384] buffer.
// Row order: [pre0..3, post0..3, res0..3 | res4..15]
//   rows 0..11  -> lane-half A outputs, rows 12..23 -> lane-half B outputs
// ---------------------------------------------------------------------------
__global__ void repack_kernel(
    const float4* __restrict__ pre4,
    const float4* __restrict__ post4,
    const float4* __restrict__ res4,
    float4* __restrict__ phiws4)
{
    const int idx = blockIdx.x * blockDim.x + threadIdx.x;   // 0 .. 24*4096-1
    if (idx >= 24 * NC4) return;
    const int row = idx / NC4;
    const int k4  = idx % NC4;
    float4 v;
    if (row < 4)        v = pre4[row * NC4 + k4];
    else if (row < 8)   v = post4[(row - 4) * NC4 + k4];
    else                v = res4[(row - 8) * NC4 + k4];   // rows 8..23 -> res0..15
    phiws4[idx] = v;
}

// ---------------------------------------------------------------------------
// Kernel 1: projections. Grid = (B_ROWS/4) x 2 K-halves -> 2048 blocks.
// Block = 4 batch rows x one K-half; 4 waves = K-eighths.
// Within a wave: lanes 0-31 (half A) accumulate outputs {pre0-3, post0-3,
// res0-3, ssq}; lanes 32-63 (half B) accumulate {res4-15}. Both halves read
// identical x addresses (HW broadcast); phi rows differ per half via the
// repacked phiws layout. Partial dots written per K-half; finalize sums.
// NOTE: launch_bounds(256,4) — NOT 8. At min-8-waves/EU the allocator is
// capped at 64 VGPR and spills ~85 live floats to scratch (R3: 2.4 GB scratch
// writes, 5x slowdown). At (256,4) this body compiles to 64 VGPR with no
// spill (R2-verified), which already permits 8 waves/SIMD at runtime.
// ---------------------------------------------------------------------------
__global__ __launch_bounds__(256, 4) void proj_kernel(
    const float* __restrict__ x,
    const float* __restrict__ phiws,
    float* __restrict__ dots_part)   // [2][B_ROWS][25]
{
    const float4* __restrict__ x4    = reinterpret_cast<const float4*>(x);
    const float4* __restrict__ phi4  = reinterpret_cast<const float4*>(phiws);

    const int bid  = blockIdx.x;
    const int kb   = bid & 1;            // K-half
    const int b0   = (bid >> 1) * 4;     // first batch row
    const int wave = threadIdx.x >> 6;
    const int lane = threadIdx.x & 63;
    const int half = lane >> 5;          // 0 = group A, 1 = group B
    const int l31  = lane & 31;
    const int phirow0 = half * 12;       // first phiws row for this half

    float acc[4][13];
#pragma unroll
    for (int r = 0; r < 4; ++r)
#pragma unroll
        for (int j = 0; j < 13; ++j) acc[r][j] = 0.f;

    // this block covers float4 indices [kb*2048, kb*2048+2048); wave gets 512
    const int kbase = kb * 2048 + wave * 512;

    for (int s = 0; s < 16; ++s) {
        const int k4 = kbase + s * 32 + l31;

        float4 xv[4];
#pragma unroll
        for (int r = 0; r < 4; ++r)
            xv[r] = x4[(size_t)(b0 + r) * NC4 + k4];

        // ssq (both halves compute it over identical addresses; only A's is used)
#pragma unroll
        for (int r = 0; r < 4; ++r)
            acc[r][12] += xv[r].x*xv[r].x + xv[r].y*xv[r].y
                        + xv[r].z*xv[r].z + xv[r].w*xv[r].w;

        // 12 phi rows for this half, staged in groups of 4 to limit live regs
#pragma unroll
        for (int g = 0; g < 3; ++g) {
            float4 p[4];
#pragma unroll
            for (int jj = 0; jj < 4; ++jj)
                p[jj] = phi4[(size_t)(phirow0 + g * 4 + jj) * NC4 + k4];
#pragma unroll
            for (int jj = 0; jj < 4; ++jj)
#pragma unroll
                for (int r = 0; r < 4; ++r)
                    acc[r][g * 4 + jj] += xv[r].x*p[jj].x + xv[r].y*p[jj].y
                                        + xv[r].z*p[jj].z + xv[r].w*p[jj].w;
        }
    }

    // butterfly reduce within each 32-lane half (offsets < 32 stay in-half)
#pragma unroll
    for (int r = 0; r < 4; ++r)
#pragma unroll
        for (int j = 0; j < 13; ++j) {
            float v = acc[r][j];
#pragma unroll
            for (int off = 16; off > 0; off >>= 1)
                v += __shfl_xor(v, off, 64);
            acc[r][j] = v;
        }

    __shared__ float red[4][2][4][13];   // [wave][half][row][j]
    if (l31 < 13) {
#pragma unroll
        for (int r = 0; r < 4; ++r)
            red[wave][half][r][l31] = acc[r][l31];
    }
    __syncthreads();

    // final cross-wave sum; 100 threads -> dots_part[kb][4 rows][25]
    const int t = threadIdx.x;
    if (t < 100) {
        const int r = t / 25, o = t % 25;
        int h, j;
        if (o < 12)      { h = 0; j = o; }        // pre0-3, post0-3, res0-3
        else if (o < 24) { h = 1; j = o - 12; }   // res4-15
        else             { h = 0; j = 12; }       // ssq
        const float s = red[0][h][r][j] + red[1][h][r][j]
                      + red[2][h][r][j] + red[3][h][r][j];
        dots_part[((size_t)kb * B_ROWS + (b0 + r)) * 25 + o] = s;
    }
}

// ---------------------------------------------------------------------------
// Kernel 2: per-row finalize: sum K-halves, rms factor, softmax, 2*sigmoid,
// Sinkhorn(20).
// dots layout: [0..3]=pre, [4..7]=post, [8..23]=res, [24]=ssq
// params layout: [0..3]=H_pre, [4..7]=H_post, [8..23]=M (row-major 4x4)
// ---------------------------------------------------------------------------
__global__ void finalize_kernel(
    const float* __restrict__ dots_part,
    const float* __restrict__ b_pre,
    const float* __restrict__ b_post,
    const float* __restrict__ b_res,
    const float* __restrict__ alpha_pre,
    const float* __restrict__ alpha_post,
    const float* __restrict__ alpha_res,
    float* __restrict__ params)
{
    const int row = blockIdx.x * blockDim.x + threadIdx.x;
    if (row >= B_ROWS) return;

    const float* d0 = dots_part + (size_t)row * 25;
    const float* d1 = dots_part + ((size_t)B_ROWS + row) * 25;
    float d[25];
#pragma unroll
    for (int o = 0; o < 25; ++o) d[o] = d0[o] + d1[o];

    const float inv_rms = rsqrtf(d[24] * (1.f / (float)NC) + 1e-8f);
    const float ap  = alpha_pre[0];
    const float apo = alpha_post[0];
    const float ar  = alpha_res[0];

    // softmax(h_pre)
    float hp[4];
    float mx = -1e30f;
#pragma unroll
    for (int j = 0; j < 4; ++j) {
        hp[j] = ap * d[j] * inv_rms + b_pre[j];
        mx = fmaxf(mx, hp[j]);
    }
    float e[4], s = 0.f;
#pragma unroll
    for (int j = 0; j < 4; ++j) { e[j] = expf(hp[j] - mx); s += e[j]; }
    float Hpre[4];
#pragma unroll
    for (int j = 0; j < 4; ++j) Hpre[j] = e[j] / s;

    // 2*sigmoid(h_post)
    float Hpost[4];
#pragma unroll
    for (int j = 0; j < 4; ++j) {
        const float h = apo * d[4 + j] * inv_rms + b_post[j];
        Hpost[j] = 2.f / (1.f + expf(-h));
    }

    // Sinkhorn on exp(h_res)
    float M[16];
#pragma unroll
    for (int k = 0; k < 16; ++k)
        M[k] = expf(ar * d[8 + k] * inv_rms + b_res[k]);

    for (int it = 0; it < 20; ++it) {
#pragma unroll
        for (int i = 0; i < 4; ++i) {
            const float rs = M[i*4+0] + M[i*4+1] + M[i*4+2] + M[i*4+3] + 1e-8f;
#pragma unroll
            for (int j = 0; j < 4; ++j) M[i*4+j] = M[i*4+j] / rs;
        }
#pragma unroll
        for (int j = 0; j < 4; ++j) {
            const float cs = M[0*4+j] + M[1*4+j] + M[2*4+j] + M[3*4+j] + 1e-8f;
#pragma unroll
            for (int i = 0; i < 4; ++i) M[i*4+j] = M[i*4+j] / cs;
        }
    }

    float* p = params + (size_t)row * 24;
#pragma unroll
    for (int j = 0; j < 4; ++j)  p[j]     = Hpre[j];
#pragma unroll
    for (int j = 0; j < 4; ++j)  p[4 + j] = Hpost[j];
#pragma unroll
    for (int k = 0; k < 16; ++k) p[8 + k] = M[k];
}

// ---------------------------------------------------------------------------
// Kernel 3: output. One block per batch row; x row held in registers
// (64 floats/thread), block-reduced RMS of x_agg, then fused epilogue.
// ---------------------------------------------------------------------------
__global__ __launch_bounds__(256, 2) void out_kernel(
    const float* __restrict__ x,
    const float* __restrict__ w,
    const float* __restrict__ params,
    float* __restrict__ out)
{
    const float4* __restrict__ x4 = reinterpret_cast<const float4*>(x);
    const float4* __restrict__ w4 = reinterpret_cast<const float4*>(w);
    float4* __restrict__ out4 = reinterpret_cast<float4*>(out);

    const int b = blockIdx.x;
    const float* __restrict__ p = params + (size_t)b * 24;

    float Hpre[4], Hpost[4], M[16];
#pragma unroll
    for (int j = 0; j < 4; ++j)  Hpre[j]  = p[j];
#pragma unroll
    for (int j = 0; j < 4; ++j)  Hpost[j] = p[4 + j];
#pragma unroll
    for (int k = 0; k < 16; ++k) M[k]     = p[8 + k];

    const int t = threadIdx.x;
    const size_t base = (size_t)b * NC4;

    float4 xv[4][4];  // [u][stream]
    float4 agg[4];
    float ssq = 0.f;

#pragma unroll
    for (int u = 0; u < 4; ++u) {
        const int c4 = u * 256 + t;
#pragma unroll
        for (int n = 0; n < 4; ++n)
            xv[u][n] = x4[base + (size_t)n * C4 + c4];

        float4 a;
        a.x = Hpre[0]*xv[u][0].x + Hpre[1]*xv[u][1].x + Hpre[2]*xv[u][2].x + Hpre[3]*xv[u][3].x;
        a.y = Hpre[0]*xv[u][0].y + Hpre[1]*xv[u][1].y + Hpre[2]*xv[u][2].y + Hpre[3]*xv[u][3].y;
        a.z = Hpre[0]*xv[u][0].z + Hpre[1]*xv[u][1].z + Hpre[2]*xv[u][2].z + Hpre[3]*xv[u][3].z;
        a.w = Hpre[0]*xv[u][0].w + Hpre[1]*xv[u][1].w + Hpre[2]*xv[u][2].w + Hpre[3]*xv[u][3].w;
        agg[u] = a;
        ssq += a.x*a.x + a.y*a.y + a.z*a.z + a.w*a.w;
    }

    // block-wide sum of ssq
#pragma unroll
    for (int off = 32; off > 0; off >>= 1)
        ssq += __shfl_xor(ssq, off, 64);
    __shared__ float red[4];
    if ((t & 63) == 0) red[t >> 6] = ssq;
    __syncthreads();
    const float total = red[0] + red[1] + red[2] + red[3];
    const float inv = rsqrtf(total * (1.f / (float)C_DIM) + 1e-5f);

#pragma unroll
    for (int u = 0; u < 4; ++u) {
        const int c4 = u * 256 + t;
        const float4 wv = w4[c4];
        float4 y;
        y.x = agg[u].x * inv * wv.x;
        y.y = agg[u].y * inv * wv.y;
        y.z = agg[u].z * inv * wv.z;
        y.w = agg[u].w * inv * wv.w;

#pragma unroll
        for (int i = 0; i < 4; ++i) {
            float4 o;
            o.x = Hpost[i]*y.x + M[i*4+0]*xv[u][0].x + M[i*4+1]*xv[u][1].x
                               + M[i*4+2]*xv[u][2].x + M[i*4+3]*xv[u][3].x;
            o.y = Hpost[i]*y.y + M[i*4+0]*xv[u][0].y + M[i*4+1]*xv[u][1].y
                               + M[i*4+2]*xv[u][2].y + M[i*4+3]*xv[u][3].y;
            o.z = Hpost[i]*y.z + M[i*4+0]*xv[u][0].z + M[i*4+1]*xv[u][1].z
                               + M[i*4+2]*xv[u][2].z + M[i*4+3]*xv[u][3].z;
            o.w = Hpost[i]*y.w + M[i*4+0]*xv[u][0].w + M[i*4+1]*xv[u][1].w
                               + M[i*4+2]*xv[u][2].w + M[i*4+3]*xv[u][3].w;
            out4[base + (size_t)i * C4 + c4] = o;
        }
    }
}

// ---------------------------------------------------------------------------
extern "C" void kernel_launch(void* const* d_in, const int* in_sizes, int n_in,
                              void* d_out, int out_size, void* d_ws, size_t ws_size,
                              hipStream_t stream) {
    const float* x        = (const float*)d_in[0];
    const float* w        = (const float*)d_in[1];
    const float* phi_pre  = (const float*)d_in[2];
    const float* phi_post = (const float*)d_in[3];
    const float* phi_res  = (const float*)d_in[4];
    const float* b_pre    = (const float*)d_in[5];
    const float* b_post   = (const float*)d_in[6];
    const float* b_res    = (const float*)d_in[7];
    const float* a_pre    = (const float*)d_in[8];
    const float* a_post   = (const float*)d_in[9];
    const float* a_res    = (const float*)d_in[10];
    float* out = (float*)d_out;

    float* dots_part = (float*)d_ws;                        // [2][4096][25]
    float* params    = dots_part + (size_t)2 * B_ROWS * 25; // [4096][24]
    float* phiws     = params + (size_t)B_ROWS * 24;        // [24][16384]

    hipLaunchKernelGGL(repack_kernel, dim3((24 * NC4 + 255) / 256), dim3(256), 0, stream,
                       (const float4*)phi_pre, (const float4*)phi_post,
                       (const float4*)phi_res, (float4*)phiws);
    hipLaunchKernelGGL(proj_kernel, dim3(B_ROWS / 2), dim3(256), 0, stream,
                       x, phiws, dots_part);
    hipLaunchKernelGGL(finalize_kernel, dim3(B_ROWS / 256), dim3(256), 0, stream,
                       dots_part, b_pre, b_post, b_res, a_pre, a_post, a_res, params);
    hipLaunchKernelGGL(out_kernel, dim3(B_ROWS), dim3(256), 0, stream,
                       x, w, params, out);
}

// Round 5
// 294.953 us; speedup vs baseline: 4.1990x; 1.0756x over previous
//
#include <hip/hip_runtime.h>
#include <math.h>

#define B_ROWS 4096
#define NSTR 4
#define C_DIM 4096
#define NC 16384      // NSTR*C_DIM
#define NC4 4096      // NC/4 (float4 per batch row)
#define C4 1024       // C_DIM/4 (float4 per stream)

// ---------------------------------------------------------------------------
// Kernel 0: repack phi into one contiguous [24][16384] buffer.
// Natural row order: [pre0..3, post0..3, res0..15]
// ---------------------------------------------------------------------------
__global__ void repack_kernel(
    const float4* __restrict__ pre4,
    const float4* __restrict__ post4,
    const float4* __restrict__ res4,
    float4* __restrict__ phiws4)
{
    const int idx = blockIdx.x * blockDim.x + threadIdx.x;   // 0 .. 24*4096-1
    if (idx >= 24 * NC4) return;
    const int row = idx / NC4;
    const int k4  = idx % NC4;
    float4 v;
    if (row < 4)        v = pre4[row * NC4 + k4];
    else if (row < 8)   v = post4[(row - 4) * NC4 + k4];
    else                v = res4[(row - 8) * NC4 + k4];
    phiws4[idx] = v;
}

// ---------------------------------------------------------------------------
// Kernel 1: projections. Grid = (B_ROWS/4) x 2 K-halves -> 2048 blocks.
// Block = 4 batch rows x one K-half. The 24 outputs are split 8 ways:
// wave w (0-3) x lane-half h handles phi rows w*6 + h*3 + {0,1,2} over the
// FULL K-half. ssq of batch row w is accumulated by wave w (one extra load,
// L1/L2-hit since it aliases one of the xv streams).
// Per-lane live state: 12 acc + 1 ssq + 16 xv + 4 xw + 12 p + addr ~= 55
// -> fits 64 VGPR with NO AGPR shuffling and NO scratch alloca (all register
// arrays statically indexed; epilogue writes are static loops). R4's design
// kept 84+ floats live at a 64-VGPR report -> compiler used AGPR round-trips
// (3.3x VALU inflation) and capped occupancy at ~4 waves/SIMD.
// Cost accepted: x re-read by all 4 waves of a block (served by L2).
// ---------------------------------------------------------------------------
__global__ __launch_bounds__(256, 4) void proj_kernel(
    const float* __restrict__ x,
    const float* __restrict__ phiws,
    float* __restrict__ dots_part)   // [2][B_ROWS][25]
{
    const float4* __restrict__ x4   = reinterpret_cast<const float4*>(x);
    const float4* __restrict__ phi4 = reinterpret_cast<const float4*>(phiws);

    const int bid  = blockIdx.x;
    const int kb   = bid & 1;            // K-half
    const int b0   = (bid >> 1) * 4;     // first batch row
    const int wave = threadIdx.x >> 6;
    const int lane = threadIdx.x & 63;
    const int half = lane >> 5;          // lane-half within wave
    const int l31  = lane & 31;

    const int kbase = kb * 2048;         // float4 index where this K-half starts

    // per-lane stream bases (float4 units)
    const float4* __restrict__ xbase   = x4 + (size_t)b0 * NC4 + kbase + l31;
    const float4* __restrict__ xwbase  = x4 + (size_t)(b0 + wave) * NC4 + kbase + l31;
    const float4* __restrict__ phibase = phi4 + (size_t)(wave * 6 + half * 3) * NC4 + kbase + l31;

    float acc[4][3];                     // [batch row][phi row j]
#pragma unroll
    for (int r = 0; r < 4; ++r)
#pragma unroll
        for (int j = 0; j < 3; ++j) acc[r][j] = 0.f;
    float ssq = 0.f;                     // sum x^2 of batch row `wave`

    for (int s = 0; s < 64; ++s) {
        const int off = s * 32;

        float4 xv[4];
#pragma unroll
        for (int r = 0; r < 4; ++r)
            xv[r] = xbase[(size_t)r * NC4 + off];

        const float4 xw = xwbase[off];
        ssq += xw.x*xw.x + xw.y*xw.y + xw.z*xw.z + xw.w*xw.w;

        float4 p[3];
#pragma unroll
        for (int j = 0; j < 3; ++j)
            p[j] = phibase[(size_t)j * NC4 + off];

#pragma unroll
        for (int j = 0; j < 3; ++j)
#pragma unroll
            for (int r = 0; r < 4; ++r)
                acc[r][j] += xv[r].x*p[j].x + xv[r].y*p[j].y
                           + xv[r].z*p[j].z + xv[r].w*p[j].w;
    }

    // butterfly reduce within each 32-lane half (each half independently
    // covers all columns of the K-half, so in-half reduction is complete)
#pragma unroll
    for (int r = 0; r < 4; ++r)
#pragma unroll
        for (int j = 0; j < 3; ++j) {
            float v = acc[r][j];
#pragma unroll
            for (int off = 16; off > 0; off >>= 1)
                v += __shfl_xor(v, off, 64);
            acc[r][j] = v;
        }
#pragma unroll
    for (int off = 16; off > 0; off >>= 1)
        ssq += __shfl_xor(ssq, off, 64);

    // stage to LDS with STATIC indexing only
    __shared__ float red[4][2][13];      // [wave][half][r*3+j | 12=ssq]
    if (l31 == 0) {
#pragma unroll
        for (int r = 0; r < 4; ++r)
#pragma unroll
            for (int j = 0; j < 3; ++j)
                red[wave][half][r * 3 + j] = acc[r][j];
        red[wave][half][12] = ssq;       // both halves write the same value
    }
    __syncthreads();

    // final gather; 100 threads -> dots_part[kb][4 rows][25]
    const int t = threadIdx.x;
    if (t < 100) {
        const int r = t / 25, o = t % 25;
        float s;
        if (o < 24) {
            const int w  = o / 6;
            const int hf = (o % 6) / 3;
            const int j  = o % 3;
            s = red[w][hf][r * 3 + j];
        } else {
            s = red[r][0][12];           // ssq of row r lives in wave r
        }
        dots_part[((size_t)kb * B_ROWS + (b0 + r)) * 25 + o] = s;
    }
}

// ---------------------------------------------------------------------------
// Kernel 2: per-row finalize: sum K-halves, rms factor, softmax, 2*sigmoid,
// Sinkhorn(20).
// dots layout: [0..3]=pre, [4..7]=post, [8..23]=res, [24]=ssq
// params layout: [0..3]=H_pre, [4..7]=H_post, [8..23]=M (row-major 4x4)
// ---------------------------------------------------------------------------
__global__ void finalize_kernel(
    const float* __restrict__ dots_part,
    const float* __restrict__ b_pre,
    const float* __restrict__ b_post,
    const float* __restrict__ b_res,
    const float* __restrict__ alpha_pre,
    const float* __restrict__ alpha_post,
    const float* __restrict__ alpha_res,
    float* __restrict__ params)
{
    const int row = blockIdx.x * blockDim.x + threadIdx.x;
    if (row >= B_ROWS) return;

    const float* d0 = dots_part + (size_t)row * 25;
    const float* d1 = dots_part + ((size_t)B_ROWS + row) * 25;
    float d[25];
#pragma unroll
    for (int o = 0; o < 25; ++o) d[o] = d0[o] + d1[o];

    const float inv_rms = rsqrtf(d[24] * (1.f / (float)NC) + 1e-8f);
    const float ap  = alpha_pre[0];
    const float apo = alpha_post[0];
    const float ar  = alpha_res[0];

    // softmax(h_pre)
    float hp[4];
    float mx = -1e30f;
#pragma unroll
    for (int j = 0; j < 4; ++j) {
        hp[j] = ap * d[j] * inv_rms + b_pre[j];
        mx = fmaxf(mx, hp[j]);
    }
    float e[4], s = 0.f;
#pragma unroll
    for (int j = 0; j < 4; ++j) { e[j] = expf(hp[j] - mx); s += e[j]; }
    float Hpre[4];
#pragma unroll
    for (int j = 0; j < 4; ++j) Hpre[j] = e[j] / s;

    // 2*sigmoid(h_post)
    float Hpost[4];
#pragma unroll
    for (int j = 0; j < 4; ++j) {
        const float h = apo * d[4 + j] * inv_rms + b_post[j];
        Hpost[j] = 2.f / (1.f + expf(-h));
    }

    // Sinkhorn on exp(h_res)
    float M[16];
#pragma unroll
    for (int k = 0; k < 16; ++k)
        M[k] = expf(ar * d[8 + k] * inv_rms + b_res[k]);

    for (int it = 0; it < 20; ++it) {
#pragma unroll
        for (int i = 0; i < 4; ++i) {
            const float rs = M[i*4+0] + M[i*4+1] + M[i*4+2] + M[i*4+3] + 1e-8f;
#pragma unroll
            for (int j = 0; j < 4; ++j) M[i*4+j] = M[i*4+j] / rs;
        }
#pragma unroll
        for (int j = 0; j < 4; ++j) {
            const float cs = M[0*4+j] + M[1*4+j] + M[2*4+j] + M[3*4+j] + 1e-8f;
#pragma unroll
            for (int i = 0; i < 4; ++i) M[i*4+j] = M[i*4+j] / cs;
        }
    }

    float* p = params + (size_t)row * 24;
#pragma unroll
    for (int j = 0; j < 4; ++j)  p[j]     = Hpre[j];
#pragma unroll
    for (int j = 0; j < 4; ++j)  p[4 + j] = Hpost[j];
#pragma unroll
    for (int k = 0; k < 16; ++k) p[8 + k] = M[k];
}

// ---------------------------------------------------------------------------
// Kernel 3: output. One block per batch row; x row held in registers
// (64 floats/thread), block-reduced RMS of x_agg, then fused epilogue.
// ---------------------------------------------------------------------------
__global__ __launch_bounds__(256, 2) void out_kernel(
    const float* __restrict__ x,
    const float* __restrict__ w,
    const float* __restrict__ params,
    float* __restrict__ out)
{
    const float4* __restrict__ x4 = reinterpret_cast<const float4*>(x);
    const float4* __restrict__ w4 = reinterpret_cast<const float4*>(w);
    float4* __restrict__ out4 = reinterpret_cast<float4*>(out);

    const int b = blockIdx.x;
    const float* __restrict__ p = params + (size_t)b * 24;

    float Hpre[4], Hpost[4], M[16];
#pragma unroll
    for (int j = 0; j < 4; ++j)  Hpre[j]  = p[j];
#pragma unroll
    for (int j = 0; j < 4; ++j)  Hpost[j] = p[4 + j];
#pragma unroll
    for (int k = 0; k < 16; ++k) M[k]     = p[8 + k];

    const int t = threadIdx.x;
    const size_t base = (size_t)b * NC4;

    float4 xv[4][4];  // [u][stream]
    float4 agg[4];
    float ssq = 0.f;

#pragma unroll
    for (int u = 0; u < 4; ++u) {
        const int c4 = u * 256 + t;
#pragma unroll
        for (int n = 0; n < 4; ++n)
            xv[u][n] = x4[base + (size_t)n * C4 + c4];

        float4 a;
        a.x = Hpre[0]*xv[u][0].x + Hpre[1]*xv[u][1].x + Hpre[2]*xv[u][2].x + Hpre[3]*xv[u][3].x;
        a.y = Hpre[0]*xv[u][0].y + Hpre[1]*xv[u][1].y + Hpre[2]*xv[u][2].y + Hpre[3]*xv[u][3].y;
        a.z = Hpre[0]*xv[u][0].z + Hpre[1]*xv[u][1].z + Hpre[2]*xv[u][2].z + Hpre[3]*xv[u][3].z;
        a.w = Hpre[0]*xv[u][0].w + Hpre[1]*xv[u][1].w + Hpre[2]*xv[u][2].w + Hpre[3]*xv[u][3].w;
        agg[u] = a;
        ssq += a.x*a.x + a.y*a.y + a.z*a.z + a.w*a.w;
    }

    // block-wide sum of ssq
#pragma unroll
    for (int off = 32; off > 0; off >>= 1)
        ssq += __shfl_xor(ssq, off, 64);
    __shared__ float red[4];
    if ((t & 63) == 0) red[t >> 6] = ssq;
    __syncthreads();
    const float total = red[0] + red[1] + red[2] + red[3];
    const float inv = rsqrtf(total * (1.f / (float)C_DIM) + 1e-5f);

#pragma unroll
    for (int u = 0; u < 4; ++u) {
        const int c4 = u * 256 + t;
        const float4 wv = w4[c4];
        float4 y;
        y.x = agg[u].x * inv * wv.x;
        y.y = agg[u].y * inv * wv.y;
        y.z = agg[u].z * inv * wv.z;
        y.w = agg[u].w * inv * wv.w;

#pragma unroll
        for (int i = 0; i < 4; ++i) {
            float4 o;
            o.x = Hpost[i]*y.x + M[i*4+0]*xv[u][0].x + M[i*4+1]*xv[u][1].x
                               + M[i*4+2]*xv[u][2].x + M[i*4+3]*xv[u][3].x;
            o.y = Hpost[i]*y.y + M[i*4+0]*xv[u][0].y + M[i*4+1]*xv[u][1].y
                               + M[i*4+2]*xv[u][2].y + M[i*4+3]*xv[u][3].y;
            o.z = Hpost[i]*y.z + M[i*4+0]*xv[u][0].z + M[i*4+1]*xv[u][1].z
                               + M[i*4+2]*xv[u][2].z + M[i*4+3]*xv[u][3].z;
            o.w = Hpost[i]*y.w + M[i*4+0]*xv[u][0].w + M[i*4+1]*xv[u][1].w
                               + M[i*4+2]*xv[u][2].w + M[i*4+3]*xv[u][3].w;
            out4[base + (size_t)i * C4 + c4] = o;
        }
    }
}

// ---------------------------------------------------------------------------
extern "C" void kernel_launch(void* const* d_in, const int* in_sizes, int n_in,
                              void* d_out, int out_size, void* d_ws, size_t ws_size,
                              hipStream_t stream) {
    const float* x        = (const float*)d_in[0];
    const float* w        = (const float*)d_in[1];
    const float* phi_pre  = (const float*)d_in[2];
    const float* phi_post = (const float*)d_in[3];
    const float* phi_res  = (const float*)d_in[4];
    const float* b_pre    = (const float*)d_in[5];
    const float* b_post   = (const float*)d_in[6];
    const float* b_res    = (const float*)d_in[7];
    const float* a_pre    = (const float*)d_in[8];
    const float* a_post   = (const float*)d_in[9];
    const float* a_res    = (const float*)d_in[10];
    float* out = (float*)d_out;

    float* dots_part = (float*)d_ws;                        // [2][4096][25]
    float* params    = dots_part + (size_t)2 * B_ROWS * 25; // [4096][24]
    float* phiws     = params + (size_t)B_ROWS * 24;        // [24][16384]

    hipLaunchKernelGGL(repack_kernel, dim3((24 * NC4 + 255) / 256), dim3(256), 0, stream,
                       (const float4*)phi_pre, (const float4*)phi_post,
                       (const float4*)phi_res, (float4*)phiws);
    hipLaunchKernelGGL(proj_kernel, dim3(B_ROWS / 2), dim3(256), 0, stream,
                       x, phiws, dots_part);
    hipLaunchKernelGGL(finalize_kernel, dim3(B_ROWS / 256), dim3(256), 0, stream,
                       dots_part, b_pre, b_post, b_res, a_pre, a_post, a_res, params);
    hipLaunchKernelGGL(out_kernel, dim3(B_ROWS), dim3(256), 0, stream,
                       x, w, params, out);
}

// Round 6
// 290.895 us; speedup vs baseline: 4.2576x; 1.0139x over previous
//
#include <hip/hip_runtime.h>
#include <math.h>

#define B_ROWS 4096
#define NSTR 4
#define C_DIM 4096
#define NC 16384      // NSTR*C_DIM
#define NC4 4096      // NC/4 (float4 per batch row)
#define C4 1024       // C_DIM/4 (float4 per stream)

// ---------------------------------------------------------------------------
// Kernel 0: repack phi into one contiguous [24][16384] buffer.
// Natural row order: [pre0..3, post0..3, res0..15]
// ---------------------------------------------------------------------------
__global__ void repack_kernel(
    const float4* __restrict__ pre4,
    const float4* __restrict__ post4,
    const float4* __restrict__ res4,
    float4* __restrict__ phiws4)
{
    const int idx = blockIdx.x * blockDim.x + threadIdx.x;   // 0 .. 24*4096-1
    if (idx >= 24 * NC4) return;
    const int row = idx / NC4;
    const int k4  = idx % NC4;
    float4 v;
    if (row < 4)        v = pre4[row * NC4 + k4];
    else if (row < 8)   v = post4[(row - 4) * NC4 + k4];
    else                v = res4[(row - 8) * NC4 + k4];
    phiws4[idx] = v;
}

// ---------------------------------------------------------------------------
// Kernel 1: projections. Grid = (B_ROWS/4) x 2 K-halves -> 2048 blocks.
// Block = 4 batch rows x one K-half. The 24 outputs are split 8 ways:
// wave w (0-3) x lane-half h handles phi rows w*6 + h*3 + {0,1,2} over the
// FULL K-half. ssq of batch row w is accumulated by wave w.
//
// R5 LESSON: identical structure at 52 VGPR ran latency-bound (~1040
// cyc/iter): compiler had no registers to keep loads in flight and
// serialized load->wait->consume. out_kernel (16 indep loads up-front, 64
// regs of data) sustains ~6-8 TB/s on the SAME access shapes. So here: 2x
// unroll, ALL 18 float4 loads issued before any FMA -> 18 loads in flight.
// Live floats ~ 13 acc + 72 load data + addr ~= 95 -> fits 128-VGPR cap at
// (256,4), statically indexed everywhere (no AGPR/scratch round-trips).
// ---------------------------------------------------------------------------
__global__ __launch_bounds__(256, 4) void proj_kernel(
    const float* __restrict__ x,
    const float* __restrict__ phiws,
    float* __restrict__ dots_part)   // [2][B_ROWS][25]
{
    const float4* __restrict__ x4   = reinterpret_cast<const float4*>(x);
    const float4* __restrict__ phi4 = reinterpret_cast<const float4*>(phiws);

    const int bid  = blockIdx.x;
    const int kb   = bid & 1;            // K-half
    const int b0   = (bid >> 1) * 4;     // first batch row
    const int wave = threadIdx.x >> 6;
    const int lane = threadIdx.x & 63;
    const int half = lane >> 5;          // lane-half within wave
    const int l31  = lane & 31;

    const int kbase = kb * 2048;         // float4 index where this K-half starts

    // per-lane stream bases (float4 units)
    const float4* __restrict__ xbase   = x4 + (size_t)b0 * NC4 + kbase + l31;
    const float4* __restrict__ xwbase  = x4 + (size_t)(b0 + wave) * NC4 + kbase + l31;
    const float4* __restrict__ phibase = phi4 + (size_t)(wave * 6 + half * 3) * NC4 + kbase + l31;

    float acc[4][3];                     // [batch row][phi row j]
#pragma unroll
    for (int r = 0; r < 4; ++r)
#pragma unroll
        for (int j = 0; j < 3; ++j) acc[r][j] = 0.f;
    float ssq = 0.f;                     // sum x^2 of batch row `wave`

    for (int s = 0; s < 64; s += 2) {
        const int off0 = s * 32;
        const int off1 = off0 + 32;

        // ---- issue ALL 18 loads before any consumption ----
        float4 xa[4], xb[4];
#pragma unroll
        for (int r = 0; r < 4; ++r)
            xa[r] = xbase[(size_t)r * NC4 + off0];
#pragma unroll
        for (int r = 0; r < 4; ++r)
            xb[r] = xbase[(size_t)r * NC4 + off1];

        float4 pa[3], pb[3];
#pragma unroll
        for (int j = 0; j < 3; ++j)
            pa[j] = phibase[(size_t)j * NC4 + off0];
#pragma unroll
        for (int j = 0; j < 3; ++j)
            pb[j] = phibase[(size_t)j * NC4 + off1];

        const float4 xwa = xwbase[off0];
        const float4 xwb = xwbase[off1];

        // ---- consume ----
        ssq += xwa.x*xwa.x + xwa.y*xwa.y + xwa.z*xwa.z + xwa.w*xwa.w;
        ssq += xwb.x*xwb.x + xwb.y*xwb.y + xwb.z*xwb.z + xwb.w*xwb.w;

#pragma unroll
        for (int j = 0; j < 3; ++j)
#pragma unroll
            for (int r = 0; r < 4; ++r)
                acc[r][j] += xa[r].x*pa[j].x + xa[r].y*pa[j].y
                           + xa[r].z*pa[j].z + xa[r].w*pa[j].w;
#pragma unroll
        for (int j = 0; j < 3; ++j)
#pragma unroll
            for (int r = 0; r < 4; ++r)
                acc[r][j] += xb[r].x*pb[j].x + xb[r].y*pb[j].y
                           + xb[r].z*pb[j].z + xb[r].w*pb[j].w;
    }

    // butterfly reduce within each 32-lane half (each half independently
    // covers all columns of the K-half, so in-half reduction is complete)
#pragma unroll
    for (int r = 0; r < 4; ++r)
#pragma unroll
        for (int j = 0; j < 3; ++j) {
            float v = acc[r][j];
#pragma unroll
            for (int off = 16; off > 0; off >>= 1)
                v += __shfl_xor(v, off, 64);
            acc[r][j] = v;
        }
#pragma unroll
    for (int off = 16; off > 0; off >>= 1)
        ssq += __shfl_xor(ssq, off, 64);

    // stage to LDS with STATIC indexing only
    __shared__ float red[4][2][13];      // [wave][half][r*3+j | 12=ssq]
    if (l31 == 0) {
#pragma unroll
        for (int r = 0; r < 4; ++r)
#pragma unroll
            for (int j = 0; j < 3; ++j)
                red[wave][half][r * 3 + j] = acc[r][j];
        red[wave][half][12] = ssq;       // both halves write the same value
    }
    __syncthreads();

    // final gather; 100 threads -> dots_part[kb][4 rows][25]
    const int t = threadIdx.x;
    if (t < 100) {
        const int r = t / 25, o = t % 25;
        float s;
        if (o < 24) {
            const int w  = o / 6;
            const int hf = (o % 6) / 3;
            const int j  = o % 3;
            s = red[w][hf][r * 3 + j];
        } else {
            s = red[r][0][12];           // ssq of row r lives in wave r
        }
        dots_part[((size_t)kb * B_ROWS + (b0 + r)) * 25 + o] = s;
    }
}

// ---------------------------------------------------------------------------
// Kernel 2: per-row finalize: sum K-halves, rms factor, softmax, 2*sigmoid,
// Sinkhorn(20).
// dots layout: [0..3]=pre, [4..7]=post, [8..23]=res, [24]=ssq
// params layout: [0..3]=H_pre, [4..7]=H_post, [8..23]=M (row-major 4x4)
// ---------------------------------------------------------------------------
__global__ void finalize_kernel(
    const float* __restrict__ dots_part,
    const float* __restrict__ b_pre,
    const float* __restrict__ b_post,
    const float* __restrict__ b_res,
    const float* __restrict__ alpha_pre,
    const float* __restrict__ alpha_post,
    const float* __restrict__ alpha_res,
    float* __restrict__ params)
{
    const int row = blockIdx.x * blockDim.x + threadIdx.x;
    if (row >= B_ROWS) return;

    const float* d0 = dots_part + (size_t)row * 25;
    const float* d1 = dots_part + ((size_t)B_ROWS + row) * 25;
    float d[25];
#pragma unroll
    for (int o = 0; o < 25; ++o) d[o] = d0[o] + d1[o];

    const float inv_rms = rsqrtf(d[24] * (1.f / (float)NC) + 1e-8f);
    const float ap  = alpha_pre[0];
    const float apo = alpha_post[0];
    const float ar  = alpha_res[0];

    // softmax(h_pre)
    float hp[4];
    float mx = -1e30f;
#pragma unroll
    for (int j = 0; j < 4; ++j) {
        hp[j] = ap * d[j] * inv_rms + b_pre[j];
        mx = fmaxf(mx, hp[j]);
    }
    float e[4], s = 0.f;
#pragma unroll
    for (int j = 0; j < 4; ++j) { e[j] = expf(hp[j] - mx); s += e[j]; }
    float Hpre[4];
#pragma unroll
    for (int j = 0; j < 4; ++j) Hpre[j] = e[j] / s;

    // 2*sigmoid(h_post)
    float Hpost[4];
#pragma unroll
    for (int j = 0; j < 4; ++j) {
        const float h = apo * d[4 + j] * inv_rms + b_post[j];
        Hpost[j] = 2.f / (1.f + expf(-h));
    }

    // Sinkhorn on exp(h_res)
    float M[16];
#pragma unroll
    for (int k = 0; k < 16; ++k)
        M[k] = expf(ar * d[8 + k] * inv_rms + b_res[k]);

    for (int it = 0; it < 20; ++it) {
#pragma unroll
        for (int i = 0; i < 4; ++i) {
            const float rs = M[i*4+0] + M[i*4+1] + M[i*4+2] + M[i*4+3] + 1e-8f;
#pragma unroll
            for (int j = 0; j < 4; ++j) M[i*4+j] = M[i*4+j] / rs;
        }
#pragma unroll
        for (int j = 0; j < 4; ++j) {
            const float cs = M[0*4+j] + M[1*4+j] + M[2*4+j] + M[3*4+j] + 1e-8f;
#pragma unroll
            for (int i = 0; i < 4; ++i) M[i*4+j] = M[i*4+j] / cs;
        }
    }

    float* p = params + (size_t)row * 24;
#pragma unroll
    for (int j = 0; j < 4; ++j)  p[j]     = Hpre[j];
#pragma unroll
    for (int j = 0; j < 4; ++j)  p[4 + j] = Hpost[j];
#pragma unroll
    for (int k = 0; k < 16; ++k) p[8 + k] = M[k];
}

// ---------------------------------------------------------------------------
// Kernel 3: output. One block per batch row; x row held in registers
// (64 floats/thread), block-reduced RMS of x_agg, then fused epilogue.
// ---------------------------------------------------------------------------
__global__ __launch_bounds__(256, 2) void out_kernel(
    const float* __restrict__ x,
    const float* __restrict__ w,
    const float* __restrict__ params,
    float* __restrict__ out)
{
    const float4* __restrict__ x4 = reinterpret_cast<const float4*>(x);
    const float4* __restrict__ w4 = reinterpret_cast<const float4*>(w);
    float4* __restrict__ out4 = reinterpret_cast<float4*>(out);

    const int b = blockIdx.x;
    const float* __restrict__ p = params + (size_t)b * 24;

    float Hpre[4], Hpost[4], M[16];
#pragma unroll
    for (int j = 0; j < 4; ++j)  Hpre[j]  = p[j];
#pragma unroll
    for (int j = 0; j < 4; ++j)  Hpost[j] = p[4 + j];
#pragma unroll
    for (int k = 0; k < 16; ++k) M[k]     = p[8 + k];

    const int t = threadIdx.x;
    const size_t base = (size_t)b * NC4;

    float4 xv[4][4];  // [u][stream]
    float4 agg[4];
    float ssq = 0.f;

#pragma unroll
    for (int u = 0; u < 4; ++u) {
        const int c4 = u * 256 + t;
#pragma unroll
        for (int n = 0; n < 4; ++n)
            xv[u][n] = x4[base + (size_t)n * C4 + c4];

        float4 a;
        a.x = Hpre[0]*xv[u][0].x + Hpre[1]*xv[u][1].x + Hpre[2]*xv[u][2].x + Hpre[3]*xv[u][3].x;
        a.y = Hpre[0]*xv[u][0].y + Hpre[1]*xv[u][1].y + Hpre[2]*xv[u][2].y + Hpre[3]*xv[u][3].y;
        a.z = Hpre[0]*xv[u][0].z + Hpre[1]*xv[u][1].z + Hpre[2]*xv[u][2].z + Hpre[3]*xv[u][3].z;
        a.w = Hpre[0]*xv[u][0].w + Hpre[1]*xv[u][1].w + Hpre[2]*xv[u][2].w + Hpre[3]*xv[u][3].w;
        agg[u] = a;
        ssq += a.x*a.x + a.y*a.y + a.z*a.z + a.w*a.w;
    }

    // block-wide sum of ssq
#pragma unroll
    for (int off = 32; off > 0; off >>= 1)
        ssq += __shfl_xor(ssq, off, 64);
    __shared__ float red[4];
    if ((t & 63) == 0) red[t >> 6] = ssq;
    __syncthreads();
    const float total = red[0] + red[1] + red[2] + red[3];
    const float inv = rsqrtf(total * (1.f / (float)C_DIM) + 1e-5f);

#pragma unroll
    for (int u = 0; u < 4; ++u) {
        const int c4 = u * 256 + t;
        const float4 wv = w4[c4];
        float4 y;
        y.x = agg[u].x * inv * wv.x;
        y.y = agg[u].y * inv * wv.y;
        y.z = agg[u].z * inv * wv.z;
        y.w = agg[u].w * inv * wv.w;

#pragma unroll
        for (int i = 0; i < 4; ++i) {
            float4 o;
            o.x = Hpost[i]*y.x + M[i*4+0]*xv[u][0].x + M[i*4+1]*xv[u][1].x
                               + M[i*4+2]*xv[u][2].x + M[i*4+3]*xv[u][3].x;
            o.y = Hpost[i]*y.y + M[i*4+0]*xv[u][0].y + M[i*4+1]*xv[u][1].y
                               + M[i*4+2]*xv[u][2].y + M[i*4+3]*xv[u][3].y;
            o.z = Hpost[i]*y.z + M[i*4+0]*xv[u][0].z + M[i*4+1]*xv[u][1].z
                               + M[i*4+2]*xv[u][2].z + M[i*4+3]*xv[u][3].z;
            o.w = Hpost[i]*y.w + M[i*4+0]*xv[u][0].w + M[i*4+1]*xv[u][1].w
                               + M[i*4+2]*xv[u][2].w + M[i*4+3]*xv[u][3].w;
            out4[base + (size_t)i * C4 + c4] = o;
        }
    }
}

// ---------------------------------------------------------------------------
extern "C" void kernel_launch(void* const* d_in, const int* in_sizes, int n_in,
                              void* d_out, int out_size, void* d_ws, size_t ws_size,
                              hipStream_t stream) {
    const float* x        = (const float*)d_in[0];
    const float* w        = (const float*)d_in[1];
    const float* phi_pre  = (const float*)d_in[2];
    const float* phi_post = (const float*)d_in[3];
    const float* phi_res  = (const float*)d_in[4];
    const float* b_pre    = (const float*)d_in[5];
    const float* b_post   = (const float*)d_in[6];
    const float* b_res    = (const float*)d_in[7];
    const float* a_pre    = (const float*)d_in[8];
    const float* a_post   = (const float*)d_in[9];
    const float* a_res    = (const float*)d_in[10];
    float* out = (float*)d_out;

    float* dots_part = (float*)d_ws;                        // [2][4096][25]
    float* params    = dots_part + (size_t)2 * B_ROWS * 25; // [4096][24]
    float* phiws     = params + (size_t)B_ROWS * 24;        // [24][16384]

    hipLaunchKernelGGL(repack_kernel, dim3((24 * NC4 + 255) / 256), dim3(256), 0, stream,
                       (const float4*)phi_pre, (const float4*)phi_post,
                       (const float4*)phi_res, (float4*)phiws);
    hipLaunchKernelGGL(proj_kernel, dim3(B_ROWS / 2), dim3(256), 0, stream,
                       x, phiws, dots_part);
    hipLaunchKernelGGL(finalize_kernel, dim3(B_ROWS / 256), dim3(256), 0, stream,
                       dots_part, b_pre, b_post, b_res, a_pre, a_post, a_res, params);
    hipLaunchKernelGGL(out_kernel, dim3(B_ROWS), dim3(256), 0, stream,
                       x, w, params, out);
}